// Round 1
// baseline (1223.661 us; speedup 1.0000x reference)
//
#include <hip/hip_runtime.h>
#include <hip/hip_bf16.h>

#define CN 32
#define CIN 64
#define CH 64
#define CW 64
#define COUT 128

// block: (64,4,1) -> lane = w (coalesced), ty picks 8-channel group
// grid: (4 co-groups of 32, 64 h, 32 n)
__global__ __launch_bounds__(256) void conv_direct_f32(
    const float* __restrict__ x,     // (N, CIN, H, W)
    const float* __restrict__ wgt,   // (CIN*3*3, COUT), patch idx = c*9+i*3+j
    const float* __restrict__ bias,  // (COUT)
    float* __restrict__ out)         // (N, COUT, H, W)
{
    const int w   = threadIdx.x;          // 0..63
    const int ty  = threadIdx.y;          // 0..3
    const int cog = blockIdx.x;           // 0..3
    const int h   = blockIdx.y;           // 0..63
    const int n   = blockIdx.z;           // 0..31
    const int co0 = cog * 32 + ty * 8;    // 8 channels per thread

    float acc[8];
    #pragma unroll
    for (int k = 0; k < 8; ++k) acc[k] = bias[co0 + k];

    const float* xn = x + (size_t)n * CIN * CH * CW;

    for (int c = 0; c < CIN; ++c) {
        const float* xc = xn + (size_t)c * CH * CW;
        #pragma unroll
        for (int i = 0; i < 3; ++i) {
            const int hh = h - 1 + i;
            if (hh < 0 || hh >= CH) continue;   // wave-uniform (h is per-block)
            const float* xr = xc + hh * CW;
            #pragma unroll
            for (int j = 0; j < 3; ++j) {
                const int ww = w - 1 + j;
                const float v = (ww >= 0 && ww < CW) ? xr[ww] : 0.0f;
                const float* wp = wgt + (size_t)((c * 9 + i * 3 + j) * COUT) + co0;
                const float4 w0 = *reinterpret_cast<const float4*>(wp);
                const float4 w1 = *reinterpret_cast<const float4*>(wp + 4);
                acc[0] += v * w0.x;
                acc[1] += v * w0.y;
                acc[2] += v * w0.z;
                acc[3] += v * w0.w;
                acc[4] += v * w1.x;
                acc[5] += v * w1.y;
                acc[6] += v * w1.z;
                acc[7] += v * w1.w;
            }
        }
    }

    float* op = out + (((size_t)n * COUT + co0) * CH + h) * CW + w;
    #pragma unroll
    for (int k = 0; k < 8; ++k) op[(size_t)k * CH * CW] = acc[k];
}

extern "C" void kernel_launch(void* const* d_in, const int* in_sizes, int n_in,
                              void* d_out, int out_size, void* d_ws, size_t ws_size,
                              hipStream_t stream) {
    const float* x    = (const float*)d_in[0];
    const float* wgt  = (const float*)d_in[1];
    const float* bias = (const float*)d_in[2];
    float* out        = (float*)d_out;

    dim3 block(64, 4, 1);
    dim3 grid(4, 64, 32);
    conv_direct_f32<<<grid, block, 0, stream>>>(x, wgt, bias, out);
}

// Round 2
// 121.112 us; speedup vs baseline: 10.1035x; 10.1035x over previous
//
#include <hip/hip_runtime.h>
#include <cstdint>
#include <cstddef>

#define CIN   64
#define CH_   64
#define CW_   64
#define COUT  128

typedef short  s16x8  __attribute__((ext_vector_type(8)));
typedef float  f32x16 __attribute__((ext_vector_type(16)));

__device__ __forceinline__ unsigned short f32_to_bf16(float f) {
    unsigned int u = __builtin_bit_cast(unsigned int, f);
    u = u + 0x7FFFu + ((u >> 16) & 1u);          // RNE
    return (unsigned short)(u >> 16);
}

#define GLD_LDS16(g, l) __builtin_amdgcn_global_load_lds(                      \
    (const __attribute__((address_space(1))) void*)(g),                        \
    (__attribute__((address_space(3))) void*)(l), 16, 0, 0)

// ---------------- pre-kernel: f32 weights -> bf16, [tap][co][c], pre-swizzled
__global__ void wconv_prep(const float* __restrict__ wgt, unsigned short* __restrict__ wdst) {
    int tid = blockIdx.x * 256 + threadIdx.x;
    if (tid >= 9 * 128 * 64) return;
    int tap = tid >> 13;            // /8192
    int rem = tid & 8191;
    int co  = rem >> 6;
    int c   = rem & 63;
    float f = wgt[(c * 9 + tap) * COUT + co];
    // linear byte off = tap*16384 + co*128 + (c>>3)*16 + (c&7)*2, chunk XOR'd by co&7
    int off = tap * 16384 + co * 128 + ((((c >> 3) ^ (co & 7))) << 4) + (c & 7) * 2;
    wdst[off >> 1] = f32_to_bf16(f);
}

// ---------------- main: implicit GEMM, 128(spatial) x 128(co) tile per block
__global__ __launch_bounds__(256, 2) void conv_mfma(
    const float* __restrict__ x,          // (N,64,64,64) f32
    const float* __restrict__ bias,       // (128)
    const unsigned short* __restrict__ wbf, // pre-swizzled bf16 weights in ws
    float* __restrict__ out)              // (N,128,64,64) f32
{
    __shared__ __align__(16) unsigned char lds_x[4 * 66 * 128];   // 33792 B: [r][col][c] bf16, swizzled
    __shared__ __align__(16) unsigned char lds_w[2][128 * 128];   // 2 x 16384 B: [co][c] bf16, swizzled

    const int tid  = threadIdx.x;
    const int lane = tid & 63;
    const int wid  = tid >> 6;        // 0..3
    const int hi   = lane >> 5;       // 0/1
    const int l31  = lane & 31;
    const int wm   = wid >> 1;        // h-row within tile
    const int wn   = wid & 1;         // co half
    const int hb   = blockIdx.x;      // 0..31  (h pair)
    const int n    = blockIdx.y;      // 0..31
    const int h0   = hb * 2;

    const char* wsrc = (const char*)wbf;
    const int   boff = wid * 4096;

    // stage tap-0 weights into buf 0 (linear dest; source pre-swizzled)
    #pragma unroll
    for (int k = 0; k < 4; ++k)
        GLD_LDS16(wsrc + boff + k * 1024 + lane * 16, &lds_w[0][boff + k * 1024]);

    // stage x tile: rows h0-1..h0+2, cols -1..64, all 64 ch, bf16 swizzled
    {
        const float* xn = x + (size_t)n * CIN * CH_ * CW_;
        for (int idx = tid; idx < 4 * 8 * 66; idx += 256) {
            int col = idx % 66;
            int rh  = idx / 66;
            int ck  = rh & 7;         // c-chunk (8 channels)
            int r   = rh >> 3;        // 0..3
            int grow = h0 - 1 + r;
            int gcol = col - 1;
            bool v = (grow >= 0) && (grow < CH_) && (gcol >= 0) && (gcol < CW_);
            s16x8 pk;
            #pragma unroll
            for (int e = 0; e < 8; ++e) {
                float f = v ? xn[((size_t)(ck * 8 + e) * CH_ + grow) * CW_ + gcol] : 0.0f;
                pk[e] = (short)f32_to_bf16(f);
            }
            int off = (r * 66 + col) * 128 + ((ck ^ (col & 7)) << 4);
            *(s16x8*)(lds_x + off) = pk;
        }
    }
    __syncthreads();   // full drain once (x ds_writes + tap0 stage)

    f32x16 acc00 = {}, acc01 = {}, acc10 = {}, acc11 = {};

    const int          coB  = wn * 64 + l31;
    const unsigned int bOff = (unsigned)coB * 128;
    const int          xorB = l31 & 7;

    #pragma unroll
    for (int tap = 0; tap < 9; ++tap) {
        const int cur = tap & 1;
        if (tap < 8) {
            #pragma unroll
            for (int k = 0; k < 4; ++k)
                GLD_LDS16(wsrc + (tap + 1) * 16384 + boff + k * 1024 + lane * 16,
                          &lds_w[cur ^ 1][boff + k * 1024]);
            asm volatile("s_waitcnt vmcnt(4)" ::: "memory");   // tap's stage done; next stays in flight
        } else {
            asm volatile("s_waitcnt vmcnt(0)" ::: "memory");
        }
        __builtin_amdgcn_s_barrier();

        const int i = tap / 3, j = tap % 3;
        const int r    = wm + i;                       // x-tile row
        const int colj = l31 + j;
        const unsigned int aBase = (unsigned)(r * 66 + colj) * 128;
        const int          xorA  = colj & 7;

        #pragma unroll
        for (int cc = 0; cc < 4; ++cc) {               // K = 64 ch in 4 steps of 16
            const int ch = cc * 2 + hi;                // c-chunk index
            const unsigned int aO0 = aBase + (unsigned)((ch ^ xorA) << 4);
            const unsigned int aO1 = aO0 + 32 * 128;
            const unsigned int bO0 = bOff + (unsigned)((ch ^ xorB) << 4);
            const unsigned int bO1 = bO0 + 32 * 128;
            s16x8 a0 = *(const s16x8*)(lds_x + aO0);
            s16x8 a1 = *(const s16x8*)(lds_x + aO1);
            s16x8 b0 = *(const s16x8*)(lds_w[cur] + bO0);
            s16x8 b1 = *(const s16x8*)(lds_w[cur] + bO1);
            acc00 = __builtin_amdgcn_mfma_f32_32x32x16_bf16(a0, b0, acc00, 0, 0, 0);
            acc01 = __builtin_amdgcn_mfma_f32_32x32x16_bf16(a0, b1, acc01, 0, 0, 0);
            acc10 = __builtin_amdgcn_mfma_f32_32x32x16_bf16(a1, b0, acc10, 0, 0, 0);
            acc11 = __builtin_amdgcn_mfma_f32_32x32x16_bf16(a1, b1, acc11, 0, 0, 0);
        }
        __builtin_amdgcn_s_barrier();
    }

    // epilogue: D row=(reg&3)+8*(reg>>2)+4*hi (w), col=l31 (co)
    const int h = h0 + wm;
    #pragma unroll
    for (int fn = 0; fn < 2; ++fn) {
        const int co = wn * 64 + fn * 32 + l31;
        const float bv = bias[co];
        float* op = out + (((size_t)n * COUT + co) * CH_ + h) * CW_ + 4 * hi;
        #pragma unroll
        for (int fm = 0; fm < 2; ++fm) {
            const f32x16 a = fn == 0 ? (fm == 0 ? acc00 : acc10)
                                     : (fm == 0 ? acc01 : acc11);
            #pragma unroll
            for (int q = 0; q < 4; ++q) {
                float4 v = make_float4(a[4*q+0] + bv, a[4*q+1] + bv,
                                       a[4*q+2] + bv, a[4*q+3] + bv);
                *(float4*)(op + fm * 32 + 8 * q) = v;
            }
        }
    }
}

// ---------------- fallback (ws too small): round-0 direct kernel
__global__ __launch_bounds__(256) void conv_direct_f32(
    const float* __restrict__ x, const float* __restrict__ wgt,
    const float* __restrict__ bias, float* __restrict__ out)
{
    const int w = threadIdx.x, ty = threadIdx.y;
    const int cog = blockIdx.x, h = blockIdx.y, n = blockIdx.z;
    const int co0 = cog * 32 + ty * 8;
    float acc[8];
    #pragma unroll
    for (int k = 0; k < 8; ++k) acc[k] = bias[co0 + k];
    const float* xn = x + (size_t)n * CIN * CH_ * CW_;
    for (int c = 0; c < CIN; ++c) {
        const float* xc = xn + (size_t)c * CH_ * CW_;
        #pragma unroll
        for (int i = 0; i < 3; ++i) {
            const int hh = h - 1 + i;
            if (hh < 0 || hh >= CH_) continue;
            const float* xr = xc + hh * CW_;
            #pragma unroll
            for (int j = 0; j < 3; ++j) {
                const int ww = w - 1 + j;
                const float v = (ww >= 0 && ww < CW_) ? xr[ww] : 0.0f;
                const float* wp = wgt + (size_t)((c * 9 + i * 3 + j) * COUT) + co0;
                const float4 w0 = *reinterpret_cast<const float4*>(wp);
                const float4 w1 = *reinterpret_cast<const float4*>(wp + 4);
                acc[0] += v * w0.x; acc[1] += v * w0.y; acc[2] += v * w0.z; acc[3] += v * w0.w;
                acc[4] += v * w1.x; acc[5] += v * w1.y; acc[6] += v * w1.z; acc[7] += v * w1.w;
            }
        }
    }
    float* op = out + (((size_t)n * COUT + co0) * CH_ + h) * CW_ + w;
    #pragma unroll
    for (int k = 0; k < 8; ++k) op[(size_t)k * CH_ * CW_] = acc[k];
}

extern "C" void kernel_launch(void* const* d_in, const int* in_sizes, int n_in,
                              void* d_out, int out_size, void* d_ws, size_t ws_size,
                              hipStream_t stream) {
    const float* x    = (const float*)d_in[0];
    const float* wgt  = (const float*)d_in[1];
    const float* bias = (const float*)d_in[2];
    float* out        = (float*)d_out;

    if (ws_size >= 9 * 128 * 64 * sizeof(unsigned short)) {
        wconv_prep<<<288, 256, 0, stream>>>(wgt, (unsigned short*)d_ws);
        conv_mfma<<<dim3(32, 32), 256, 0, stream>>>(x, bias, (const unsigned short*)d_ws, out);
    } else {
        conv_direct_f32<<<dim3(4, 64, 32), dim3(64, 4, 1), 0, stream>>>(x, wgt, bias, out);
    }
}

// Round 3
// 114.055 us; speedup vs baseline: 10.7287x; 1.0619x over previous
//
#include <hip/hip_runtime.h>
#include <cstdint>
#include <cstddef>

#define CIN   64
#define CH_   64
#define CW_   64
#define COUT  128

typedef short  s16x8  __attribute__((ext_vector_type(8)));
typedef float  f32x16 __attribute__((ext_vector_type(16)));

__device__ __forceinline__ unsigned short f32_to_bf16(float f) {
    unsigned int u = __builtin_bit_cast(unsigned int, f);
    u = u + 0x7FFFu + ((u >> 16) & 1u);          // RNE
    return (unsigned short)(u >> 16);
}

// ---- pre-kernel: f32 (C*9, 128) -> bf16 [tap][chunk][co][8ch], fully coalesced reads
__global__ __launch_bounds__(256) void wconv_prep(const float* __restrict__ wgt,
                                                  unsigned short* __restrict__ wdst) {
    int tid = blockIdx.x * 256 + threadIdx.x;
    if (tid >= 576 * 128) return;
    int row = tid >> 7;            // c*9 + tap
    int co  = tid & 127;
    int c   = row / 9;             // compiler magic-div
    int tap = row - c * 9;
    float f = wgt[tid];            // coalesced
    wdst[((tap * 8 + (c >> 3)) * 128 + co) * 8 + (c & 7)] = f32_to_bf16(f);
}

// ---- main: implicit GEMM, 128(spatial=2h x 64w) x 128(co) per block, barrier-free tap loop
__global__ __launch_bounds__(256, 3) void conv_mfma(
    const float* __restrict__ x,            // (N,64,64,64) f32
    const float* __restrict__ bias,         // (128)
    const unsigned short* __restrict__ wbf, // bf16 [tap][chunk][co][8], in ws (L2-resident)
    float* __restrict__ out)                // (N,128,64,64) f32
{
    __shared__ __align__(16) unsigned char lds_x[4 * 66 * 128];   // 33792 B, XOR-swizzled

    const int tid  = threadIdx.x;
    const int lane = tid & 63;
    const int wid  = tid >> 6;
    const int hi   = lane >> 5;
    const int l31  = lane & 31;
    const int wm   = wid >> 1;
    const int wn   = wid & 1;

    // XCD-bijective swizzle: 1024 blocks = 8 * 128
    const int bid = blockIdx.x;
    const int swz = (bid & 7) * 128 + (bid >> 3);
    const int n   = swz >> 5;
    const int hb  = swz & 31;
    const int h0  = hb * 2;

    const float* xn = x + (size_t)n * CIN * CH_ * CW_;

    // ---- stage x tile: rows h0-1..h0+2, cols -1..64 (t=0..65), 64ch bf16, swizzled
    #pragma unroll
    for (int it = 0; it < 2; ++it) {
        const int idx = tid + it * 256;         // 512 items
        const int g  = idx & 15;                // w-group of 4
        const int ck = (idx >> 4) & 7;          // channel chunk
        const int r  = idx >> 7;                // tile row 0..3
        const int grow = h0 - 1 + r;
        s16x8 pk[4] = {};
        if (grow >= 0 && grow < CH_) {
            #pragma unroll
            for (int e = 0; e < 8; ++e) {
                const float4 v = *(const float4*)(xn + ((size_t)(ck * 8 + e) * CH_ + grow) * CW_ + 4 * g);
                pk[0][e] = (short)f32_to_bf16(v.x);
                pk[1][e] = (short)f32_to_bf16(v.y);
                pk[2][e] = (short)f32_to_bf16(v.z);
                pk[3][e] = (short)f32_to_bf16(v.w);
            }
        }
        #pragma unroll
        for (int q = 0; q < 4; ++q) {
            const int t = 4 * g + 1 + q;
            *(s16x8*)(lds_x + (r * 66 + t) * 128 + ((ck ^ (t & 7)) << 4)) = pk[q];
        }
    }
    if (tid < 64) {   // zero pads t=0 (gcol=-1) and t=65 (gcol=64)
        const int t  = (tid & 1) ? 65 : 0;
        const int ck = (tid >> 1) & 7;
        const int r  = tid >> 4;
        s16x8 z = {};
        *(s16x8*)(lds_x + (r * 66 + t) * 128 + ((ck ^ (t & 7)) << 4)) = z;
    }
    __syncthreads();   // the ONLY barrier

    f32x16 acc00 = {}, acc01 = {}, acc10 = {}, acc11 = {};
    const unsigned base0 = (unsigned)((wm * 66 + l31) * 128);
    const s16x8* wB  = (const s16x8*)wbf;
    const int bbase  = wn * 64 + l31 + hi * 128;   // frag idx within tap: +cc*256, +32 for b1

#define LOADB(dst, tap) do {                                                   \
    _Pragma("unroll") for (int cc = 0; cc < 4; ++cc) {                         \
        dst[2*cc]   = wB[(tap) * 1024 + cc * 256 + bbase];                     \
        dst[2*cc+1] = wB[(tap) * 1024 + cc * 256 + bbase + 32];                \
    } } while (0)

#define COMP(bb, tap) do {                                                     \
    const int i_ = (tap) / 3, j_ = (tap) % 3;                                  \
    const unsigned aBase = base0 + (unsigned)((i_ * 66 + j_) * 128);           \
    const int xA = (l31 + j_) & 7;                                             \
    _Pragma("unroll") for (int cc = 0; cc < 4; ++cc) {                         \
        const int ch = cc * 2 + hi;                                            \
        const unsigned aO0 = aBase + ((unsigned)(ch ^ xA) << 4);               \
        s16x8 a0 = *(const s16x8*)(lds_x + aO0);                               \
        s16x8 a1 = *(const s16x8*)(lds_x + aO0 + 32 * 128);                    \
        acc00 = __builtin_amdgcn_mfma_f32_32x32x16_bf16(a0, bb[2*cc],   acc00, 0, 0, 0); \
        acc01 = __builtin_amdgcn_mfma_f32_32x32x16_bf16(a0, bb[2*cc+1], acc01, 0, 0, 0); \
        acc10 = __builtin_amdgcn_mfma_f32_32x32x16_bf16(a1, bb[2*cc],   acc10, 0, 0, 0); \
        acc11 = __builtin_amdgcn_mfma_f32_32x32x16_bf16(a1, bb[2*cc+1], acc11, 0, 0, 0); \
    } } while (0)

    s16x8 bA[8], bB[8];
    LOADB(bA, 0);
    #pragma unroll
    for (int tt = 0; tt < 4; ++tt) {
        LOADB(bB, 2 * tt + 1);
        COMP(bA, 2 * tt);
        LOADB(bA, 2 * tt + 2);
        COMP(bB, 2 * tt + 1);
    }
    COMP(bA, 8);

    // epilogue: D row=(reg&3)+8*(reg>>2)+4*hi (w), col=l31 (co)
    const int h = h0 + wm;
    #pragma unroll
    for (int fn = 0; fn < 2; ++fn) {
        const int co = wn * 64 + fn * 32 + l31;
        const float bv = bias[co];
        float* op = out + (((size_t)n * COUT + co) * CH_ + h) * CW_ + 4 * hi;
        #pragma unroll
        for (int fm = 0; fm < 2; ++fm) {
            const f32x16 a = fn == 0 ? (fm == 0 ? acc00 : acc10)
                                     : (fm == 0 ? acc01 : acc11);
            #pragma unroll
            for (int q = 0; q < 4; ++q) {
                float4 v = make_float4(a[4*q+0] + bv, a[4*q+1] + bv,
                                       a[4*q+2] + bv, a[4*q+3] + bv);
                *(float4*)(op + fm * 32 + 8 * q) = v;
            }
        }
    }
#undef LOADB
#undef COMP
}

// ---- fallback (ws too small)
__global__ __launch_bounds__(256) void conv_direct_f32(
    const float* __restrict__ x, const float* __restrict__ wgt,
    const float* __restrict__ bias, float* __restrict__ out)
{
    const int w = threadIdx.x, ty = threadIdx.y;
    const int cog = blockIdx.x, h = blockIdx.y, n = blockIdx.z;
    const int co0 = cog * 32 + ty * 8;
    float acc[8];
    #pragma unroll
    for (int k = 0; k < 8; ++k) acc[k] = bias[co0 + k];
    const float* xn = x + (size_t)n * CIN * CH_ * CW_;
    for (int c = 0; c < CIN; ++c) {
        const float* xc = xn + (size_t)c * CH_ * CW_;
        #pragma unroll
        for (int i = 0; i < 3; ++i) {
            const int hh = h - 1 + i;
            if (hh < 0 || hh >= CH_) continue;
            const float* xr = xc + hh * CW_;
            #pragma unroll
            for (int j = 0; j < 3; ++j) {
                const int ww = w - 1 + j;
                const float v = (ww >= 0 && ww < CW_) ? xr[ww] : 0.0f;
                const float* wp = wgt + (size_t)((c * 9 + i * 3 + j) * COUT) + co0;
                const float4 w0 = *reinterpret_cast<const float4*>(wp);
                const float4 w1 = *reinterpret_cast<const float4*>(wp + 4);
                acc[0] += v * w0.x; acc[1] += v * w0.y; acc[2] += v * w0.z; acc[3] += v * w0.w;
                acc[4] += v * w1.x; acc[5] += v * w1.y; acc[6] += v * w1.z; acc[7] += v * w1.w;
            }
        }
    }
    float* op = out + (((size_t)n * COUT + co0) * CH_ + h) * CW_ + w;
    #pragma unroll
    for (int k = 0; k < 8; ++k) op[(size_t)k * CH_ * CW_] = acc[k];
}

extern "C" void kernel_launch(void* const* d_in, const int* in_sizes, int n_in,
                              void* d_out, int out_size, void* d_ws, size_t ws_size,
                              hipStream_t stream) {
    const float* x    = (const float*)d_in[0];
    const float* wgt  = (const float*)d_in[1];
    const float* bias = (const float*)d_in[2];
    float* out        = (float*)d_out;

    if (ws_size >= (size_t)(9 * 8 * 128 * 8) * sizeof(unsigned short)) {
        wconv_prep<<<288, 256, 0, stream>>>(wgt, (unsigned short*)d_ws);
        conv_mfma<<<1024, 256, 0, stream>>>(x, bias, (const unsigned short*)d_ws, out);
    } else {
        conv_direct_f32<<<dim3(4, 64, 32), dim3(64, 4, 1), 0, stream>>>(x, wgt, bias, out);
    }
}